// Round 11
// baseline (82.313 us; speedup 1.0000x reference)
//
#include <hip/hip_runtime.h>
#include <hip/hip_bf16.h>

// E3nnSimpleEdgeBlock via bf16 MFMA. R10-proven skeleton (2 edge-tiles x 2
// v-halves, LDS partial-sum reduce, unroll 4) + MFMA dependency-chain fix:
// fragments built in staggered groups, MFMAs fired in clusters targeting
// distinct accumulators so same-accumulator reuse is >=6 MFMAs or a VALU
// build-burst apart (kills in-wave MFMA result-latency stalls).
//
//   out0[e,w]   = C0*( sum_uv W000[u,v,w] a0[u]b0[v] + IS3 * sum_uv W110[u,v,w] dot(a1[u],b1[v]) )
//   out1[e,w,k] = C1*( IS3*( sum W011 a0[u]b1[v,k] + sum W101 a1[u,k]b0[v] ) + IS6*sum W111 cross_k )
//
// mfma_f32_16x16x32_bf16 lane mapping (m89-verified):
//   A[row=l&15][k=8*(l>>4)+j]  B[k=8*(l>>4)+j][col=l&15]  D[row=4*(l>>4)+r][col=l&15]

typedef __attribute__((ext_vector_type(8))) short short8;   // 8 bf16 (4 VGPRs)
typedef __attribute__((ext_vector_type(4))) float f32x4;

static constexpr float C_OUT0    = 0.022097086912079608f; // 1/sqrt(2048)
static constexpr float C_OUT1    = 0.03125f;              // 1/sqrt(1024)
static constexpr float INV_SQRT3 = 0.57735026918962576f;
static constexpr float INV_SQRT6 = 0.40824829046386302f;

static __device__ __forceinline__ short bfbits(float x) {
    __hip_bfloat16 h = __float2bfloat16(x);
    return __builtin_bit_cast(short, h);
}

// ---------------------------------------------------------------------------
// prep (unchanged, post-timing-proven x4): bf16 B-fragment stream in d_ws.
// Layout: for v, frag f (0..9), lane l: 8 bf16 = 16 B. Slice per v = 10240 B.
//   f = 2g + nf;  g: 0=W000 1=W110 2=W011 3=W101 4=W111;  w = nf*16 + (l&15)
//   element j: scale_g * Wg[(8*(l>>4)+j)*1024 + v*32 + w].  Total 327680 B.
// ---------------------------------------------------------------------------
__global__ __launch_bounds__(256) void prep_weights(
    const float* __restrict__ W000, const float* __restrict__ W110,
    const float* __restrict__ W011, const float* __restrict__ W101,
    const float* __restrict__ W111, short* __restrict__ wsB)
{
    const int t = blockIdx.x * 256 + threadIdx.x;   // 0 .. 5*32768-1
    if (t >= 5 * 32768) return;
    const int g   = t >> 15;
    const int idx = t & 32767;          // u*1024 + v*32 + w
    const int u = idx >> 10, v = (idx >> 5) & 31, w = idx & 31;
    const float* Wp = (g == 0) ? W000 : (g == 1) ? W110 : (g == 2) ? W011
                    : (g == 3) ? W101 : W111;
    const float s = (g == 0) ? C_OUT0
                  : (g == 1) ? C_OUT0 * INV_SQRT3
                  : (g == 4) ? C_OUT1 * INV_SQRT6
                  :            C_OUT1 * INV_SQRT3;
    const int f = 2 * g + (w >> 4);
    const int l = ((u >> 3) << 4) | (w & 15);
    const int j = u & 7;
    wsB[(((v * 10 + f) * 64) + l) * 8 + j] = bfbits(s * Wp[idx]);
}

// ---------------------------------------------------------------------------
// main: 256 threads = 4 waves = 2 edge-tiles (t) x 2 v-halves (vh).
// LDS 16896 B time-multiplexed: x1 stage [32][33 float4] -> bs[e][v] float4
// {b0,b1x,b1y,b1z} (stride 33) -> reduction scratch.
// ---------------------------------------------------------------------------
__global__ __launch_bounds__(256) void e3nn_ro(
    const float* __restrict__ x1, const float* __restrict__ x2,
    const short8* __restrict__ wsB, float* __restrict__ out, int E)
{
    __shared__ __align__(16) float smemf[32 * 132];   // 16896 B
    float4* smem4 = (float4*)smemf;

    const int tid   = threadIdx.x;
    const int l     = tid & 63;
    const int wv    = tid >> 6;
    const int t     = wv & 1;    // edge-tile within block
    const int vh    = wv >> 1;   // v-half: 0 -> v 0..15, 1 -> v 16..31
    const int eBase = blockIdx.x * 32;

    // ---- phase 1: stage x1 tile (32 edges x 32 float4), padded stride 33 ----
    const float4* x1v = (const float4*)x1;
    for (int i = tid; i < 32 * 32; i += 256) {
        const int e = i >> 5, c4 = i & 31;
        float4 val = {0.f, 0.f, 0.f, 0.f};
        if (eBase + e < E) val = x1v[(size_t)(eBase + e) * 32 + c4];
        smem4[e * 33 + c4] = val;
    }
    __syncthreads();

    // ---- hoist per-lane a-values (f32) into registers ----
    const int eloc = l & 15;
    const int u0   = (l >> 4) * 8;
    const float* row = smemf + (t * 16 + eloc) * 132;
    float a0r[8], a1r[3][8];
    #pragma unroll
    for (int j = 0; j < 8; ++j) {
        a0r[j] = row[u0 + j];
        #pragma unroll
        for (int c = 0; c < 3; ++c)
            a1r[c][j] = row[32 + 3 * (u0 + j) + c];
    }
    __syncthreads();   // x1 stage dead

    // ---- phase 2: bs[e][v] = {b0, b1x, b1y, b1z} f32, stride 33 float4 ----
    for (int i = tid; i < 32 * 128; i += 256) {
        const int e = i >> 7, r = i & 127;
        float val = 0.f;
        if (eBase + e < E) val = x2[(size_t)(eBase + e) * 128 + r];
        if (r < 32) {
            smemf[e * 132 + r * 4] = val;
        } else {
            const int q = r - 32, vv = q / 3, c = q - 3 * vv;
            smemf[e * 132 + vv * 4 + 1 + c] = val;
        }
    }
    __syncthreads();

    // ---- v-loop over this wave's half: 16 iters, unroll 4, clustered MFMAs ----
    const f32x4 zero = {0.f, 0.f, 0.f, 0.f};
    f32x4 acc0[2]    = {zero, zero};
    f32x4 acc1[3][2] = {{zero, zero}, {zero, zero}, {zero, zero}};

    const short8* wb    = wsB + l;
    const float4* bsrow = smem4 + (t * 16 + eloc) * 33;

    #pragma unroll 4
    for (int v = vh * 16; v < vh * 16 + 16; ++v) {
        const float4 b = bsrow[v];
        const short8* p = wb + v * 640;   // (v*10 + f)*64 + l
        short8 Bf[10];
        #pragma unroll
        for (int i = 0; i < 10; ++i) Bf[i] = p[i * 64];

        const float bv[3] = {b.y, b.z, b.w};

        // ---- build ch0 + ch1 fragments ----
        short8 Ach0, Ach1;
        #pragma unroll
        for (int j = 0; j < 8; ++j) Ach0[j] = bfbits(a0r[j] * b.x);
        #pragma unroll
        for (int j = 0; j < 8; ++j)
            Ach1[j] = bfbits(a1r[0][j] * b.y + a1r[1][j] * b.z + a1r[2][j] * b.w);

        // cluster 1: ch0 -> both nf accumulators
        acc0[0] = __builtin_amdgcn_mfma_f32_16x16x32_bf16(Ach0, Bf[0], acc0[0], 0, 0, 0);
        acc0[1] = __builtin_amdgcn_mfma_f32_16x16x32_bf16(Ach0, Bf[1], acc0[1], 0, 0, 0);

        // build A011[3] (VALU burst separates acc0 reuse)
        short8 A011[3];
        #pragma unroll
        for (int kx = 0; kx < 3; ++kx)
            #pragma unroll
            for (int j = 0; j < 8; ++j) A011[kx][j] = bfbits(a0r[j] * bv[kx]);

        // cluster 2: ch1 -> acc0 (far from cluster 1)
        acc0[0] = __builtin_amdgcn_mfma_f32_16x16x32_bf16(Ach1, Bf[2], acc0[0], 0, 0, 0);
        acc0[1] = __builtin_amdgcn_mfma_f32_16x16x32_bf16(Ach1, Bf[3], acc0[1], 0, 0, 0);

        // build A101[3]
        short8 A101[3];
        #pragma unroll
        for (int kx = 0; kx < 3; ++kx)
            #pragma unroll
            for (int j = 0; j < 8; ++j) A101[kx][j] = bfbits(a1r[kx][j] * b.x);

        // cluster 3: all W011 MFMAs (6 distinct accumulators)
        #pragma unroll
        for (int kx = 0; kx < 3; ++kx) {
            acc1[kx][0] = __builtin_amdgcn_mfma_f32_16x16x32_bf16(A011[kx], Bf[4], acc1[kx][0], 0, 0, 0);
            acc1[kx][1] = __builtin_amdgcn_mfma_f32_16x16x32_bf16(A011[kx], Bf[5], acc1[kx][1], 0, 0, 0);
        }

        // build A111[3]
        short8 A111[3];
        #pragma unroll
        for (int kx = 0; kx < 3; ++kx) {
            const int ii = (kx + 1) % 3, jj = (kx + 2) % 3;
            #pragma unroll
            for (int j = 0; j < 8; ++j)
                A111[kx][j] = bfbits(a1r[ii][j] * bv[jj] - a1r[jj][j] * bv[ii]);
        }

        // cluster 4: all W101 MFMAs (re-hits acc1[kx] ~6 MFMAs + a build after cluster 3)
        #pragma unroll
        for (int kx = 0; kx < 3; ++kx) {
            acc1[kx][0] = __builtin_amdgcn_mfma_f32_16x16x32_bf16(A101[kx], Bf[6], acc1[kx][0], 0, 0, 0);
            acc1[kx][1] = __builtin_amdgcn_mfma_f32_16x16x32_bf16(A101[kx], Bf[7], acc1[kx][1], 0, 0, 0);
        }

        // cluster 5: all W111 MFMAs (same-acc distance 6 from cluster 4)
        #pragma unroll
        for (int kx = 0; kx < 3; ++kx) {
            acc1[kx][0] = __builtin_amdgcn_mfma_f32_16x16x32_bf16(A111[kx], Bf[8], acc1[kx][0], 0, 0, 0);
            acc1[kx][1] = __builtin_amdgcn_mfma_f32_16x16x32_bf16(A111[kx], Bf[9], acc1[kx][1], 0, 0, 0);
        }
    }

    // ---- reduce the two v-halves through LDS (stride-33 rows) ----
    __syncthreads();   // all waves past their LDS b-reads

    float* red = smemf;
    const int rbase = (t * 64 + l) * 33;   // max 127*33+31 = 4222 < 4224
    if (vh == 1) {
        #pragma unroll
        for (int nf = 0; nf < 2; ++nf)
            #pragma unroll
            for (int r = 0; r < 4; ++r) {
                red[rbase + (0 + nf) * 4 + r] = acc0[nf][r];
                red[rbase + (2 + nf) * 4 + r] = acc1[0][nf][r];
                red[rbase + (4 + nf) * 4 + r] = acc1[1][nf][r];
                red[rbase + (6 + nf) * 4 + r] = acc1[2][nf][r];
            }
    }
    __syncthreads();

    // ---- epilogue from vh=0 waves (scales pre-baked into weights) ----
    if (vh == 0) {
        const int be0 = t * 16 + (l >> 4) * 4;
        #pragma unroll
        for (int nf = 0; nf < 2; ++nf) {
            const int w = nf * 16 + (l & 15);
            #pragma unroll
            for (int r = 0; r < 4; ++r) {
                const int ge = eBase + be0 + r;
                if (ge < E) {
                    const size_t base = (size_t)ge * 128;
                    out[base + w] =
                        acc0[nf][r] + red[rbase + (0 + nf) * 4 + r];
                    out[base + 32 + 3 * w + 0] =
                        acc1[0][nf][r] + red[rbase + (2 + nf) * 4 + r];
                    out[base + 32 + 3 * w + 1] =
                        acc1[1][nf][r] + red[rbase + (4 + nf) * 4 + r];
                    out[base + 32 + 3 * w + 2] =
                        acc1[2][nf][r] + red[rbase + (6 + nf) * 4 + r];
                }
            }
        }
    }
}

extern "C" void kernel_launch(void* const* d_in, const int* in_sizes, int n_in,
                              void* d_out, int out_size, void* d_ws, size_t ws_size,
                              hipStream_t stream) {
    const float* x1   = (const float*)d_in[0];
    const float* x2   = (const float*)d_in[1];
    const float* W000 = (const float*)d_in[2];
    const float* W110 = (const float*)d_in[3];
    const float* W011 = (const float*)d_in[4];
    const float* W101 = (const float*)d_in[5];
    const float* W111 = (const float*)d_in[6];
    float* out = (float*)d_out;

    const int E = in_sizes[0] / 128;

    hipLaunchKernelGGL(prep_weights, dim3((5 * 32768 + 255) / 256), dim3(256), 0, stream,
                       W000, W110, W011, W101, W111, (short*)d_ws);

    const int grid = (E + 31) / 32;
    hipLaunchKernelGGL(e3nn_ro, dim3(grid), dim3(256), 0, stream,
                       x1, x2, (const short8*)d_ws, out, E);
}

// Round 12
// 81.270 us; speedup vs baseline: 1.0128x; 1.0128x over previous
//
#include <hip/hip_runtime.h>
#include <hip/hip_bf16.h>

// E3nnSimpleEdgeBlock, two-stage factorized MFMA (R3 retry, fixed):
//   Stage 1 (MFMA, static A): G_p,c[e,w] = sum_u a_c[e,u] * (scale*Wp)[u,v,w]
//   Stage 2 (f32 VALU on D-frags): acc[e,w] += b_c[e,v] * G_p,c[e,w]
//     out0  += b0*G000 + bx*G110x + by*G110y + bz*G110z
//     out1x += bx*G011 + b0*G101x + bz*G111y - by*G111z
//     out1y += by*G011 + b0*G101y + bx*G111z - bz*G111x
//     out1z += bz*G011 + b0*G101z + by*G111x - bx*G111y
// All MFMAs use 4 once-per-wave static bf16 A-frags -> no per-v cvt/build on
// the load->MFMA path; stage-2 FMAs overlap on the separate VALU pipe.
// Fixes vs R3: conflict-free bT layout (stride 36, broadcast reads) + unroll 2.
//
// mfma_f32_16x16x32_bf16 lane mapping (m89-verified):
//   A[row=l&15][k=8*(l>>4)+j]  B[k=8*(l>>4)+j][col=l&15]  D[row=4*(l>>4)+r][col=l&15]

typedef __attribute__((ext_vector_type(8))) short short8;   // 8 bf16 (4 VGPRs)
typedef __attribute__((ext_vector_type(4))) float f32x4;

static constexpr float C_OUT0    = 0.022097086912079608f; // 1/sqrt(2048)
static constexpr float C_OUT1    = 0.03125f;              // 1/sqrt(1024)
static constexpr float INV_SQRT3 = 0.57735026918962576f;
static constexpr float INV_SQRT6 = 0.40824829046386302f;

static __device__ __forceinline__ short bfbits(float x) {
    __hip_bfloat16 h = __float2bfloat16(x);
    return __builtin_bit_cast(short, h);
}

// ---------------------------------------------------------------------------
// prep (unchanged, post-timing-proven x5): bf16 B-fragment stream in d_ws.
// Layout: for v, frag f (0..9), lane l: 8 bf16 = 16 B. Slice per v = 10240 B.
//   f = 2g + nf;  g: 0=W000 1=W110 2=W011 3=W101 4=W111;  w = nf*16 + (l&15)
//   element j: scale_g * Wg[(8*(l>>4)+j)*1024 + v*32 + w].  Total 327680 B.
// ---------------------------------------------------------------------------
__global__ __launch_bounds__(256) void prep_weights(
    const float* __restrict__ W000, const float* __restrict__ W110,
    const float* __restrict__ W011, const float* __restrict__ W101,
    const float* __restrict__ W111, short* __restrict__ wsB)
{
    const int t = blockIdx.x * 256 + threadIdx.x;   // 0 .. 5*32768-1
    if (t >= 5 * 32768) return;
    const int g   = t >> 15;
    const int idx = t & 32767;          // u*1024 + v*32 + w
    const int u = idx >> 10, v = (idx >> 5) & 31, w = idx & 31;
    const float* Wp = (g == 0) ? W000 : (g == 1) ? W110 : (g == 2) ? W011
                    : (g == 3) ? W101 : W111;
    const float s = (g == 0) ? C_OUT0
                  : (g == 1) ? C_OUT0 * INV_SQRT3
                  : (g == 4) ? C_OUT1 * INV_SQRT6
                  :            C_OUT1 * INV_SQRT3;
    const int f = 2 * g + (w >> 4);
    const int l = ((u >> 3) << 4) | (w & 15);
    const int j = u & 7;
    wsB[(((v * 10 + f) * 64) + l) * 8 + j] = bfbits(s * Wp[idx]);
}

// ---------------------------------------------------------------------------
// main: 256 threads = 4 waves = 2 edge-tiles (t) x 2 v-halves (vh).
// LDS: rawS [32][33 float4] (16896 B; x1 stage -> x2 raw -> reduce scratch)
//    + bT [128 slices][36] floats (18432 B): bT[(v*4+c)*36 + e] = b_c[e,v].
// ---------------------------------------------------------------------------
__global__ __launch_bounds__(256) void e3nn_ts(
    const float* __restrict__ x1, const float* __restrict__ x2,
    const short8* __restrict__ wsB, float* __restrict__ out, int E)
{
    __shared__ __align__(16) float rawS[32 * 132];   // 16896 B
    __shared__ __align__(16) float bT[128 * 36];     // 18432 B
    float4* raw4 = (float4*)rawS;

    const int tid   = threadIdx.x;
    const int l     = tid & 63;
    const int wv    = tid >> 6;
    const int t     = wv & 1;    // edge-tile within block
    const int vh    = wv >> 1;   // v-half: 0 -> v 0..15, 1 -> v 16..31
    const int eBase = blockIdx.x * 32;

    // ---- phase 1: stage x1 tile (32 edges x 32 float4), padded stride 33 ----
    const float4* x1v = (const float4*)x1;
    for (int i = tid; i < 32 * 32; i += 256) {
        const int e = i >> 5, c4 = i & 31;
        float4 val = {0.f, 0.f, 0.f, 0.f};
        if (eBase + e < E) val = x1v[(size_t)(eBase + e) * 32 + c4];
        raw4[e * 33 + c4] = val;
    }
    __syncthreads();

    // ---- static bf16 A-fragments (once per wave; the ONLY a-state) ----
    const int eloc = l & 15;
    const int u0   = (l >> 4) * 8;
    {
        const float* row = rawS + (t * 16 + eloc) * 132;
        // declared below after use of row
    }
    short8 Aa0, Aax, Aay, Aaz;
    {
        const float* row = rawS + (t * 16 + eloc) * 132;
        #pragma unroll
        for (int j = 0; j < 8; ++j) {
            Aa0[j] = bfbits(row[u0 + j]);
            Aax[j] = bfbits(row[32 + 3 * (u0 + j) + 0]);
            Aay[j] = bfbits(row[32 + 3 * (u0 + j) + 1]);
            Aaz[j] = bfbits(row[32 + 3 * (u0 + j) + 2]);
        }
    }
    __syncthreads();   // x1 stage dead

    // ---- phase 2a: stage x2 raw (same coalesced pattern) ----
    const float4* x2v = (const float4*)x2;
    for (int i = tid; i < 32 * 32; i += 256) {
        const int e = i >> 5, c4 = i & 31;
        float4 val = {0.f, 0.f, 0.f, 0.f};
        if (eBase + e < E) val = x2v[(size_t)(eBase + e) * 32 + c4];
        raw4[e * 33 + c4] = val;
    }
    __syncthreads();

    // ---- phase 2b: scatter to bT[(v*4+c)*36 + e] (one-time transpose) ----
    {
        const int s  = tid >> 1;        // slice = v*4 + c, 0..127
        const int eh = tid & 1;
        const int v  = s >> 2, c = s & 3;
        const int r  = (c == 0) ? v : (32 + v * 3 + (c - 1));
        #pragma unroll
        for (int ee = 0; ee < 16; ++ee) {
            const int e = eh * 16 + ee;
            bT[s * 36 + e] = rawS[e * 132 + r];
        }
    }
    __syncthreads();

    // ---- main v loop: 16 iters; 22 static-A MFMAs + 32 f32x4 stage-2 FMAs ----
    const f32x4 zero = {0.f, 0.f, 0.f, 0.f};
    f32x4 acc0[2]    = {zero, zero};
    f32x4 acc1[3][2] = {{zero, zero}, {zero, zero}, {zero, zero}};

    const short8* wb  = wsB + l;
    const float*  bTt = bT + t * 16 + (l >> 4) * 4;   // + (v*4+c)*36; 16B-aligned

    #pragma unroll 2
    for (int v = vh * 16; v < vh * 16 + 16; ++v) {
        const short8* p = wb + v * 640;   // (v*10 + f)*64 + l
        short8 Bf[10];
        #pragma unroll
        for (int f = 0; f < 10; ++f) Bf[f] = p[f * 64];

        // b-vectors for this lane's 4 D-rows (broadcast within 16-lane group)
        const f32x4 B0 = *(const f32x4*)(bTt + (v * 4 + 0) * 36);
        const f32x4 Bx = *(const f32x4*)(bTt + (v * 4 + 1) * 36);
        const f32x4 By = *(const f32x4*)(bTt + (v * 4 + 2) * 36);
        const f32x4 Bz = *(const f32x4*)(bTt + (v * 4 + 3) * 36);

        #pragma unroll
        for (int nf = 0; nf < 2; ++nf) {
            const f32x4 G000  = __builtin_amdgcn_mfma_f32_16x16x32_bf16(Aa0, Bf[0 + nf], zero, 0, 0, 0);
            const f32x4 G110x = __builtin_amdgcn_mfma_f32_16x16x32_bf16(Aax, Bf[2 + nf], zero, 0, 0, 0);
            const f32x4 G110y = __builtin_amdgcn_mfma_f32_16x16x32_bf16(Aay, Bf[2 + nf], zero, 0, 0, 0);
            const f32x4 G110z = __builtin_amdgcn_mfma_f32_16x16x32_bf16(Aaz, Bf[2 + nf], zero, 0, 0, 0);
            acc0[nf] += B0 * G000 + Bx * G110x + By * G110y + Bz * G110z;

            const f32x4 G011  = __builtin_amdgcn_mfma_f32_16x16x32_bf16(Aa0, Bf[4 + nf], zero, 0, 0, 0);
            acc1[0][nf] += Bx * G011;
            acc1[1][nf] += By * G011;
            acc1[2][nf] += Bz * G011;

            const f32x4 G101x = __builtin_amdgcn_mfma_f32_16x16x32_bf16(Aax, Bf[6 + nf], zero, 0, 0, 0);
            const f32x4 G101y = __builtin_amdgcn_mfma_f32_16x16x32_bf16(Aay, Bf[6 + nf], zero, 0, 0, 0);
            const f32x4 G101z = __builtin_amdgcn_mfma_f32_16x16x32_bf16(Aaz, Bf[6 + nf], zero, 0, 0, 0);
            acc1[0][nf] += B0 * G101x;
            acc1[1][nf] += B0 * G101y;
            acc1[2][nf] += B0 * G101z;

            const f32x4 G111x = __builtin_amdgcn_mfma_f32_16x16x32_bf16(Aax, Bf[8 + nf], zero, 0, 0, 0);
            const f32x4 G111y = __builtin_amdgcn_mfma_f32_16x16x32_bf16(Aay, Bf[8 + nf], zero, 0, 0, 0);
            const f32x4 G111z = __builtin_amdgcn_mfma_f32_16x16x32_bf16(Aaz, Bf[8 + nf], zero, 0, 0, 0);
            acc1[0][nf] += Bz * G111y - By * G111z;
            acc1[1][nf] += Bx * G111z - Bz * G111x;
            acc1[2][nf] += By * G111x - Bx * G111y;
        }
    }

    // ---- reduce the two v-halves through LDS (stride-33 rows in rawS) ----
    __syncthreads();   // all waves past their bT reads; rawS long dead

    float* red = rawS;
    const int rbase = (t * 64 + l) * 33;   // max 127*33+31 = 4222 < 4224
    if (vh == 1) {
        #pragma unroll
        for (int nf = 0; nf < 2; ++nf)
            #pragma unroll
            for (int r = 0; r < 4; ++r) {
                red[rbase + (0 + nf) * 4 + r] = acc0[nf][r];
                red[rbase + (2 + nf) * 4 + r] = acc1[0][nf][r];
                red[rbase + (4 + nf) * 4 + r] = acc1[1][nf][r];
                red[rbase + (6 + nf) * 4 + r] = acc1[2][nf][r];
            }
    }
    __syncthreads();

    // ---- epilogue from vh=0 waves (scales pre-baked into weights) ----
    if (vh == 0) {
        const int be0 = t * 16 + (l >> 4) * 4;
        #pragma unroll
        for (int nf = 0; nf < 2; ++nf) {
            const int w = nf * 16 + (l & 15);
            #pragma unroll
            for (int r = 0; r < 4; ++r) {
                const int ge = eBase + be0 + r;
                if (ge < E) {
                    const size_t base = (size_t)ge * 128;
                    out[base + w] =
                        acc0[nf][r] + red[rbase + (0 + nf) * 4 + r];
                    out[base + 32 + 3 * w + 0] =
                        acc1[0][nf][r] + red[rbase + (2 + nf) * 4 + r];
                    out[base + 32 + 3 * w + 1] =
                        acc1[1][nf][r] + red[rbase + (4 + nf) * 4 + r];
                    out[base + 32 + 3 * w + 2] =
                        acc1[2][nf][r] + red[rbase + (6 + nf) * 4 + r];
                }
            }
        }
    }
}

extern "C" void kernel_launch(void* const* d_in, const int* in_sizes, int n_in,
                              void* d_out, int out_size, void* d_ws, size_t ws_size,
                              hipStream_t stream) {
    const float* x1   = (const float*)d_in[0];
    const float* x2   = (const float*)d_in[1];
    const float* W000 = (const float*)d_in[2];
    const float* W110 = (const float*)d_in[3];
    const float* W011 = (const float*)d_in[4];
    const float* W101 = (const float*)d_in[5];
    const float* W111 = (const float*)d_in[6];
    float* out = (float*)d_out;

    const int E = in_sizes[0] / 128;

    hipLaunchKernelGGL(prep_weights, dim3((5 * 32768 + 255) / 256), dim3(256), 0, stream,
                       W000, W110, W011, W101, W111, (short*)d_ws);

    const int grid = (E + 31) / 32;
    hipLaunchKernelGGL(e3nn_ts, dim3(grid), dim3(256), 0, stream,
                       x1, x2, (const short8*)d_ws, out, E);
}

// Round 13
// 79.714 us; speedup vs baseline: 1.0326x; 1.0195x over previous
//
#include <hip/hip_runtime.h>
#include <hip/hip_bf16.h>

// E3nnSimpleEdgeBlock, two-stage factorized MFMA (R12 datapath) + occupancy fix:
//   - 16-edge tile/block, 4 waves = 4 v-quarters (8 v-iters each) -> 12500 waves
//   - LDS cut to 18688 B (rawS 8448 reused x1->x2->reduce, bT 10240)
//   - barrier-free main loop; sequential 4-way LDS reduce in epilogue
// Stage 1 (MFMA, static A): G_p,c[e,w] = sum_u a_c[e,u] * (scale*Wp)[u,v,w]
// Stage 2 (f32 VALU on D-frags): acc[e,w] += b_c[e,v] * G_p,c[e,w]
//
// mfma_f32_16x16x32_bf16 lane mapping (m89-verified):
//   A[row=l&15][k=8*(l>>4)+j]  B[k=8*(l>>4)+j][col=l&15]  D[row=4*(l>>4)+r][col=l&15]

typedef __attribute__((ext_vector_type(8))) short short8;   // 8 bf16 (4 VGPRs)
typedef __attribute__((ext_vector_type(4))) float f32x4;

static constexpr float C_OUT0    = 0.022097086912079608f; // 1/sqrt(2048)
static constexpr float C_OUT1    = 0.03125f;              // 1/sqrt(1024)
static constexpr float INV_SQRT3 = 0.57735026918962576f;
static constexpr float INV_SQRT6 = 0.40824829046386302f;

static __device__ __forceinline__ short bfbits(float x) {
    __hip_bfloat16 h = __float2bfloat16(x);
    return __builtin_bit_cast(short, h);
}

// ---------------------------------------------------------------------------
// prep (unchanged, post-timing-proven x6): bf16 B-fragment stream in d_ws.
// Layout: for v, frag f (0..9), lane l: 8 bf16 = 16 B. Slice per v = 10240 B.
//   f = 2g + nf;  g: 0=W000 1=W110 2=W011 3=W101 4=W111;  w = nf*16 + (l&15)
//   element j: scale_g * Wg[(8*(l>>4)+j)*1024 + v*32 + w].  Total 327680 B.
// ---------------------------------------------------------------------------
__global__ __launch_bounds__(256) void prep_weights(
    const float* __restrict__ W000, const float* __restrict__ W110,
    const float* __restrict__ W011, const float* __restrict__ W101,
    const float* __restrict__ W111, short* __restrict__ wsB)
{
    const int t = blockIdx.x * 256 + threadIdx.x;   // 0 .. 5*32768-1
    if (t >= 5 * 32768) return;
    const int g   = t >> 15;
    const int idx = t & 32767;          // u*1024 + v*32 + w
    const int u = idx >> 10, v = (idx >> 5) & 31, w = idx & 31;
    const float* Wp = (g == 0) ? W000 : (g == 1) ? W110 : (g == 2) ? W011
                    : (g == 3) ? W101 : W111;
    const float s = (g == 0) ? C_OUT0
                  : (g == 1) ? C_OUT0 * INV_SQRT3
                  : (g == 4) ? C_OUT1 * INV_SQRT6
                  :            C_OUT1 * INV_SQRT3;
    const int f = 2 * g + (w >> 4);
    const int l = ((u >> 3) << 4) | (w & 15);
    const int j = u & 7;
    wsB[(((v * 10 + f) * 64) + l) * 8 + j] = bfbits(s * Wp[idx]);
}

// ---------------------------------------------------------------------------
// main: 256 threads = 4 waves = 1 edge-tile (16 edges) x 4 v-quarters (vq).
// LDS 18688 B: rawS [16][33 float4] (8448; x1 stage -> x2 stage -> reduce
// scratch) + bT [128 slices][20 floats] (10240): bT[(v*4+c)*20 + e] = b_c[e,v].
// ---------------------------------------------------------------------------
__global__ __launch_bounds__(256) void e3nn_q4(
    const float* __restrict__ x1, const float* __restrict__ x2,
    const short8* __restrict__ wsB, float* __restrict__ out, int E)
{
    __shared__ __align__(16) float rawS[16 * 132];   // 8448 B
    __shared__ __align__(16) float bT[128 * 20];     // 10240 B
    float4* raw4 = (float4*)rawS;

    const int tid   = threadIdx.x;
    const int l     = tid & 63;
    const int vq    = tid >> 6;          // v-quarter: v in [8*vq, 8*vq+8)
    const int eBase = blockIdx.x * 16;

    // ---- phase 1: stage x1 tile (16 edges x 32 float4), padded stride 33 ----
    const float4* x1v = (const float4*)x1;
    for (int i = tid; i < 16 * 32; i += 256) {
        const int e = i >> 5, c4 = i & 31;
        float4 val = {0.f, 0.f, 0.f, 0.f};
        if (eBase + e < E) val = x1v[(size_t)(eBase + e) * 32 + c4];
        raw4[e * 33 + c4] = val;
    }
    __syncthreads();

    // ---- static bf16 A-fragments (identical in all 4 waves; broadcast reads) ----
    const int eloc = l & 15;
    const int u0   = (l >> 4) * 8;
    short8 Aa0, Aax, Aay, Aaz;
    {
        const float* row = rawS + eloc * 132;
        #pragma unroll
        for (int j = 0; j < 8; ++j) {
            Aa0[j] = bfbits(row[u0 + j]);
            Aax[j] = bfbits(row[32 + 3 * (u0 + j) + 0]);
            Aay[j] = bfbits(row[32 + 3 * (u0 + j) + 1]);
            Aaz[j] = bfbits(row[32 + 3 * (u0 + j) + 2]);
        }
    }
    __syncthreads();   // x1 stage dead

    // ---- phase 2a: stage x2 raw (same coalesced pattern) ----
    const float4* x2v = (const float4*)x2;
    for (int i = tid; i < 16 * 32; i += 256) {
        const int e = i >> 5, c4 = i & 31;
        float4 val = {0.f, 0.f, 0.f, 0.f};
        if (eBase + e < E) val = x2v[(size_t)(eBase + e) * 32 + c4];
        raw4[e * 33 + c4] = val;
    }
    __syncthreads();

    // ---- phase 2b: transpose to bT[(v*4+c)*20 + e] ----
    {
        const int s  = tid >> 1;        // slice = v*4 + c, 0..127
        const int eh = tid & 1;
        const int v  = s >> 2, c = s & 3;
        const int r  = (c == 0) ? v : (32 + v * 3 + (c - 1));
        #pragma unroll
        for (int k = 0; k < 8; ++k) {
            const int e = eh * 8 + k;
            bT[s * 20 + e] = rawS[e * 132 + r];
        }
    }
    __syncthreads();

    // ---- main v loop: 8 iters; 22 static-A MFMAs + 32 f32x4 stage-2 FMAs ----
    const f32x4 zero = {0.f, 0.f, 0.f, 0.f};
    f32x4 acc0[2]    = {zero, zero};
    f32x4 acc1[3][2] = {{zero, zero}, {zero, zero}, {zero, zero}};

    const short8* wb  = wsB + l;
    const float*  bTt = bT + (l >> 4) * 4;   // + (v*4+c)*20; 16B-aligned (80B*s)

    #pragma unroll 2
    for (int v = vq * 8; v < vq * 8 + 8; ++v) {
        const short8* p = wb + v * 640;   // (v*10 + f)*64 + l
        short8 Bf[10];
        #pragma unroll
        for (int f = 0; f < 10; ++f) Bf[f] = p[f * 64];

        // b-vectors for this lane's 4 D-rows (broadcast within 16-lane group)
        const f32x4 B0 = *(const f32x4*)(bTt + (v * 4 + 0) * 20);
        const f32x4 Bx = *(const f32x4*)(bTt + (v * 4 + 1) * 20);
        const f32x4 By = *(const f32x4*)(bTt + (v * 4 + 2) * 20);
        const f32x4 Bz = *(const f32x4*)(bTt + (v * 4 + 3) * 20);

        #pragma unroll
        for (int nf = 0; nf < 2; ++nf) {
            const f32x4 G000  = __builtin_amdgcn_mfma_f32_16x16x32_bf16(Aa0, Bf[0 + nf], zero, 0, 0, 0);
            const f32x4 G110x = __builtin_amdgcn_mfma_f32_16x16x32_bf16(Aax, Bf[2 + nf], zero, 0, 0, 0);
            const f32x4 G110y = __builtin_amdgcn_mfma_f32_16x16x32_bf16(Aay, Bf[2 + nf], zero, 0, 0, 0);
            const f32x4 G110z = __builtin_amdgcn_mfma_f32_16x16x32_bf16(Aaz, Bf[2 + nf], zero, 0, 0, 0);
            acc0[nf] += B0 * G000 + Bx * G110x + By * G110y + Bz * G110z;

            const f32x4 G011  = __builtin_amdgcn_mfma_f32_16x16x32_bf16(Aa0, Bf[4 + nf], zero, 0, 0, 0);
            acc1[0][nf] += Bx * G011;
            acc1[1][nf] += By * G011;
            acc1[2][nf] += Bz * G011;

            const f32x4 G101x = __builtin_amdgcn_mfma_f32_16x16x32_bf16(Aax, Bf[6 + nf], zero, 0, 0, 0);
            const f32x4 G101y = __builtin_amdgcn_mfma_f32_16x16x32_bf16(Aay, Bf[6 + nf], zero, 0, 0, 0);
            const f32x4 G101z = __builtin_amdgcn_mfma_f32_16x16x32_bf16(Aaz, Bf[6 + nf], zero, 0, 0, 0);
            acc1[0][nf] += B0 * G101x;
            acc1[1][nf] += B0 * G101y;
            acc1[2][nf] += B0 * G101z;

            const f32x4 G111x = __builtin_amdgcn_mfma_f32_16x16x32_bf16(Aax, Bf[8 + nf], zero, 0, 0, 0);
            const f32x4 G111y = __builtin_amdgcn_mfma_f32_16x16x32_bf16(Aay, Bf[8 + nf], zero, 0, 0, 0);
            const f32x4 G111z = __builtin_amdgcn_mfma_f32_16x16x32_bf16(Aaz, Bf[8 + nf], zero, 0, 0, 0);
            acc1[0][nf] += Bz * G111y - By * G111z;
            acc1[1][nf] += Bx * G111z - Bz * G111x;
            acc1[2][nf] += By * G111x - Bx * G111y;
        }
    }

    // ---- sequential 4-way reduce through rawS (64 rows x 33, conflict-free) ----
    float* red = rawS;
    const int rbase = l * 33;   // 64 rows x 33 floats = 8448 B, fits rawS

    __syncthreads();   // all waves done with bT/rawS phases
    if (vq == 3) {
        #pragma unroll
        for (int nf = 0; nf < 2; ++nf)
            #pragma unroll
            for (int r = 0; r < 4; ++r) {
                red[rbase + (0 + nf) * 4 + r] = acc0[nf][r];
                red[rbase + (2 + nf) * 4 + r] = acc1[0][nf][r];
                red[rbase + (4 + nf) * 4 + r] = acc1[1][nf][r];
                red[rbase + (6 + nf) * 4 + r] = acc1[2][nf][r];
            }
    }
    __syncthreads();
    if (vq == 2) {
        #pragma unroll
        for (int nf = 0; nf < 2; ++nf)
            #pragma unroll
            for (int r = 0; r < 4; ++r) {
                red[rbase + (0 + nf) * 4 + r] += acc0[nf][r];
                red[rbase + (2 + nf) * 4 + r] += acc1[0][nf][r];
                red[rbase + (4 + nf) * 4 + r] += acc1[1][nf][r];
                red[rbase + (6 + nf) * 4 + r] += acc1[2][nf][r];
            }
    }
    __syncthreads();
    if (vq == 1) {
        #pragma unroll
        for (int nf = 0; nf < 2; ++nf)
            #pragma unroll
            for (int r = 0; r < 4; ++r) {
                red[rbase + (0 + nf) * 4 + r] += acc0[nf][r];
                red[rbase + (2 + nf) * 4 + r] += acc1[0][nf][r];
                red[rbase + (4 + nf) * 4 + r] += acc1[1][nf][r];
                red[rbase + (6 + nf) * 4 + r] += acc1[2][nf][r];
            }
    }
    __syncthreads();

    // ---- epilogue from vq=0 wave (scales pre-baked into weights) ----
    if (vq == 0) {
        const int be0 = (l >> 4) * 4;
        #pragma unroll
        for (int nf = 0; nf < 2; ++nf) {
            const int w = nf * 16 + (l & 15);
            #pragma unroll
            for (int r = 0; r < 4; ++r) {
                const int ge = eBase + be0 + r;
                if (ge < E) {
                    const size_t base = (size_t)ge * 128;
                    out[base + w] =
                        acc0[nf][r] + red[rbase + (0 + nf) * 4 + r];
                    out[base + 32 + 3 * w + 0] =
                        acc1[0][nf][r] + red[rbase + (2 + nf) * 4 + r];
                    out[base + 32 + 3 * w + 1] =
                        acc1[1][nf][r] + red[rbase + (4 + nf) * 4 + r];
                    out[base + 32 + 3 * w + 2] =
                        acc1[2][nf][r] + red[rbase + (6 + nf) * 4 + r];
                }
            }
        }
    }
}

extern "C" void kernel_launch(void* const* d_in, const int* in_sizes, int n_in,
                              void* d_out, int out_size, void* d_ws, size_t ws_size,
                              hipStream_t stream) {
    const float* x1   = (const float*)d_in[0];
    const float* x2   = (const float*)d_in[1];
    const float* W000 = (const float*)d_in[2];
    const float* W110 = (const float*)d_in[3];
    const float* W011 = (const float*)d_in[4];
    const float* W101 = (const float*)d_in[5];
    const float* W111 = (const float*)d_in[6];
    float* out = (float*)d_out;

    const int E = in_sizes[0] / 128;

    hipLaunchKernelGGL(prep_weights, dim3((5 * 32768 + 255) / 256), dim3(256), 0, stream,
                       W000, W110, W011, W101, W111, (short*)d_ws);

    const int grid = (E + 15) / 16;
    hipLaunchKernelGGL(e3nn_q4, dim3(grid), dim3(256), 0, stream,
                       x1, x2, (const short8*)d_ws, out, E);
}